// Round 1
// baseline (517.593 us; speedup 1.0000x reference)
//
#include <hip/hip_runtime.h>
#include <hip/hip_bf16.h>

// Problem constants: B=32, S=4096, E=512, D=512, H=512
#define BATCH 32
#define SEQ   4096
#define EDIM  512
#define HDIM  512

typedef unsigned short u16;
typedef unsigned int   u32;

typedef __bf16 bf16x8 __attribute__((ext_vector_type(8)));
typedef float  f32x4  __attribute__((ext_vector_type(4)));

__device__ __forceinline__ u16 bf_rne(float x) {
    u32 u = __float_as_uint(x);
    u32 r = (u + 0x7fffu + ((u >> 16) & 1u)) >> 16;   // round-to-nearest-even
    return (u16)r;
}
__device__ __forceinline__ u32 pack2(u16 lo, u16 hi) {
    return (u32)lo | ((u32)hi << 16);
}
__device__ __forceinline__ float tanh_fast(float x) {
    // tanh(x) = 1 - 2/(e^{2x}+1); e^{2x} = 2^(x*2*log2e). ~1e-6 abs err.
    float e = __builtin_amdgcn_exp2f(x * 2.88539008177793f);
    return 1.0f - 2.0f * __builtin_amdgcn_rcpf(e + 1.0f);
}

// ---------------------------------------------------------------------------
// Kernel 0: pack W_enc [H][E] fp32 -> bf16 in b-fragment-major layout.
// Fragment chunk id = (nsub*16 + kc)*64 + lane, 16B each.
// lane needs W[nsub*16 + (lane&15)][kc*32 + (lane>>4)*8 + j], j=0..7
// (verified mfma_f32_16x16x32_bf16 B layout: B[k=(l>>4)*8+j][n=l&15] == W^T form)
// ---------------------------------------------------------------------------
__global__ void pack_w(const float* __restrict__ W, uint4* __restrict__ out) {
    int id   = blockIdx.x * 256 + threadIdx.x;      // 32768 chunks
    int nsub = id >> 10;                            // /1024 (16 kc * 64 lanes)
    int rem  = id & 1023;
    int kc   = rem >> 6;
    int lane = rem & 63;
    int row  = nsub * 16 + (lane & 15);
    int col  = kc * 32 + (lane >> 4) * 8;
    const float* src = W + row * EDIM + col;
    uint4 o;
    o.x = pack2(bf_rne(src[0]), bf_rne(src[1]));
    o.y = pack2(bf_rne(src[2]), bf_rne(src[3]));
    o.z = pack2(bf_rne(src[4]), bf_rne(src[5]));
    o.w = pack2(bf_rne(src[6]), bf_rne(src[7]));
    out[id] = o;
}

// ---------------------------------------------------------------------------
// Kernel 1: dec_bias[b][h] = dot(decoder_hidden[b], W_dec[h]) + b_dec[h] + b_enc[h]
// One wave per (b,h). 16384 outputs -> 4096 blocks x 4 waves.
// ---------------------------------------------------------------------------
__global__ void dec_proj(const float* __restrict__ dec, const float* __restrict__ Wd,
                         const float* __restrict__ b_enc, const float* __restrict__ b_dec,
                         float* __restrict__ out) {
    int wave = threadIdx.x >> 6, lane = threadIdx.x & 63;
    int p = blockIdx.x * 4 + wave;
    int b = p >> 9, h = p & 511;
    const float4* wr = reinterpret_cast<const float4*>(Wd)  + h * 128;
    const float4* dr = reinterpret_cast<const float4*>(dec) + b * 128;
    float4 w0 = wr[lane * 2], w1 = wr[lane * 2 + 1];
    float4 d0 = dr[lane * 2], d1 = dr[lane * 2 + 1];
    float s = w0.x * d0.x + w0.y * d0.y + w0.z * d0.z + w0.w * d0.w
            + w1.x * d1.x + w1.y * d1.y + w1.z * d1.z + w1.w * d1.w;
#pragma unroll
    for (int m = 1; m < 64; m <<= 1) s += __shfl_xor(s, m, 64);
    if (lane == 0) out[p] = s + b_dec[h] + b_enc[h];
}

// ---------------------------------------------------------------------------
// Kernel 2: fused enc-projection + tanh + v-dot  -> scores[131072]
// Block: 256 thr (4 waves), M-tile = 64 rows, full H=512 per block.
// Wave covers n-range wave*128 (8 nsub of 16); 4 msub of 16.
// K-loop: 16 chunks of BK=32; X fp32 staged->bf16 in LDS (stride 40: 2-way max).
// mfma_f32_16x16x32_bf16: A[m=l&15][k=(l>>4)*8+j]; C/D: m=(l>>4)*4+r, n=l&15.
// ---------------------------------------------------------------------------
__global__ __launch_bounds__(256, 2) void score_kernel(
    const float* __restrict__ X, const uint4* __restrict__ Wp,
    const float* __restrict__ bias, const float* __restrict__ v,
    float* __restrict__ scores)
{
    __shared__ alignas(16) u16 Abuf[64 * 40];   // 64 rows x (32 k + 8 pad)
    __shared__ float sred[4][64];

    const int tid  = threadIdx.x;
    const int wave = tid >> 6, lane = tid & 63;
    const int quad = lane >> 4, l15 = lane & 15;
    const int blk  = blockIdx.x;
    const long row0 = (long)blk * 64;
    const int b = blk >> 6;                      // 64 rows/block, 4096 rows/batch
    const float* Xb = X + row0 * EDIM;
    const float4* X4 = reinterpret_cast<const float4*>(Xb);

    // per-lane bias & v for the 8 nsub of this wave
    float hb[8], hv[8];
#pragma unroll
    for (int jj = 0; jj < 8; jj++) {
        int h = wave * 128 + jj * 16 + l15;
        hb[jj] = bias[b * HDIM + h];
        hv[jj] = v[h];
    }

    f32x4 acc[4][8] = {};        // [msub][nsub], 128 VGPRs
    float s_acc[16];
#pragma unroll
    for (int i = 0; i < 16; i++) s_acc[i] = 0.f;

    // staging map: chunk = 64 rows x 32 floats = 512 float4; 2 per thread
    const int r0 = tid >> 3;          // 0..31
    const int c0 = tid & 7;           // float4 col within 32-float chunk
    const int r1 = r0 + 32;

    float4 pa = X4[r0 * 128 + c0];
    float4 pb = X4[r1 * 128 + c0];

    for (int ch = 0; ch < 16; ch++) {
        __syncthreads();                               // prior reads done
        {
            u32 lo0 = pack2(bf_rne(pa.x), bf_rne(pa.y));
            u32 hi0 = pack2(bf_rne(pa.z), bf_rne(pa.w));
            u32 lo1 = pack2(bf_rne(pb.x), bf_rne(pb.y));
            u32 hi1 = pack2(bf_rne(pb.z), bf_rne(pb.w));
            uint2 s0 = make_uint2(lo0, hi0), s1 = make_uint2(lo1, hi1);
            *reinterpret_cast<uint2*>(&Abuf[r0 * 40 + c0 * 4]) = s0;
            *reinterpret_cast<uint2*>(&Abuf[r1 * 40 + c0 * 4]) = s1;
        }
        __syncthreads();
        if (ch < 15) {                                  // prefetch next chunk
            int k4 = (ch + 1) * 8;
            pa = X4[r0 * 128 + k4 + c0];
            pb = X4[r1 * 128 + k4 + c0];
        }
        // A fragments: one per msub (full BK=32 = one mfma K)
        bf16x8 af[4];
#pragma unroll
        for (int i = 0; i < 4; i++)
            af[i] = *reinterpret_cast<const bf16x8*>(&Abuf[(i * 16 + l15) * 40 + quad * 8]);
#pragma unroll
        for (int jj = 0; jj < 8; jj++) {
            int nsg = wave * 8 + jj;
            uint4 braw = Wp[(nsg * 16 + ch) * 64 + lane];
            bf16x8 bfr = __builtin_bit_cast(bf16x8, braw);
#pragma unroll
            for (int i = 0; i < 4; i++)
                acc[i][jj] = __builtin_amdgcn_mfma_f32_16x16x32_bf16(
                    af[i], bfr, acc[i][jj], 0, 0, 0);
        }
    }

    // epilogue: score contribution v[h]*tanh(acc + bias[h])
#pragma unroll
    for (int i = 0; i < 4; i++)
#pragma unroll
        for (int jj = 0; jj < 8; jj++)
#pragma unroll
            for (int r = 0; r < 4; r++) {
                float val = acc[i][jj][r] + hb[jj];
                s_acc[i * 4 + r] += hv[jj] * tanh_fast(val);
            }

    // reduce over h: butterfly over the 16 lanes of each quad (h = ...+l15)
#pragma unroll
    for (int m = 1; m < 16; m <<= 1)
#pragma unroll
        for (int x = 0; x < 16; x++)
            s_acc[x] += __shfl_xor(s_acc[x], m, 16);

    if (l15 == 0) {
#pragma unroll
        for (int x = 0; x < 16; x++) {
            int i = x >> 2, r = x & 3;
            int m = i * 16 + quad * 4 + r;
            sred[wave][m] = s_acc[x];
        }
    }
    __syncthreads();
    if (tid < 64) {
        float sc = sred[0][tid] + sred[1][tid] + sred[2][tid] + sred[3][tid];
        scores[row0 + tid] = sc;
    }
}

// ---------------------------------------------------------------------------
// Kernel 3: softmax over S per batch. 32 blocks x 256 threads, 16 vals/thread.
// ---------------------------------------------------------------------------
__global__ void softmax_k(const float* __restrict__ scores, float* __restrict__ attn) {
    __shared__ float redmax[4], redsum[4];
    int b = blockIdx.x, t = threadIdx.x;
    int wave = t >> 6, lane = t & 63;
    const float* sb = scores + b * SEQ;
    float vals[16];
    float mx = -1e30f;
#pragma unroll
    for (int i = 0; i < 16; i++) { vals[i] = sb[i * 256 + t]; mx = fmaxf(mx, vals[i]); }
#pragma unroll
    for (int m = 1; m < 64; m <<= 1) mx = fmaxf(mx, __shfl_xor(mx, m, 64));
    if (lane == 0) redmax[wave] = mx;
    __syncthreads();
    mx = fmaxf(fmaxf(redmax[0], redmax[1]), fmaxf(redmax[2], redmax[3]));
    float s = 0.f;
#pragma unroll
    for (int i = 0; i < 16; i++) {
        float e = __builtin_amdgcn_exp2f((vals[i] - mx) * 1.44269504088896f);
        vals[i] = e; s += e;
    }
#pragma unroll
    for (int m = 1; m < 64; m <<= 1) s += __shfl_xor(s, m, 64);
    if (lane == 0) redsum[wave] = s;
    __syncthreads();
    s = redsum[0] + redsum[1] + redsum[2] + redsum[3];
    float inv = 1.0f / s;
    float* ab = attn + b * SEQ;
#pragma unroll
    for (int i = 0; i < 16; i++) ab[i * 256 + t] = vals[i] * inv;
}

// ---------------------------------------------------------------------------
// Kernel 4: context[b][e] = sum_s attn[b][s] * X[b][s][e].
// 512 blocks: (b, s-chunk of 256); 256 thr, float2/thread; atomicAdd epilogue.
// ---------------------------------------------------------------------------
__global__ __launch_bounds__(256) void context_k(const float* __restrict__ X,
                                                 const float* __restrict__ attn,
                                                 float* __restrict__ out) {
    __shared__ float aw[256];
    int blk = blockIdx.x;
    int b = blk >> 4, s0 = (blk & 15) << 8;
    int t = threadIdx.x;
    aw[t] = attn[b * SEQ + s0 + t];
    __syncthreads();
    const float2* Xp = reinterpret_cast<const float2*>(X) + ((long)(b * SEQ + s0)) * 256 + t;
    float ax = 0.f, ay = 0.f;
#pragma unroll 4
    for (int s = 0; s < 256; s++) {
        float w = aw[s];
        float2 x = Xp[(long)s * 256];
        ax = fmaf(w, x.x, ax);
        ay = fmaf(w, x.y, ay);
    }
    atomicAdd(&out[b * EDIM + t * 2],     ax);
    atomicAdd(&out[b * EDIM + t * 2 + 1], ay);
}

// ---------------------------------------------------------------------------
extern "C" void kernel_launch(void* const* d_in, const int* in_sizes, int n_in,
                              void* d_out, int out_size, void* d_ws, size_t ws_size,
                              hipStream_t stream) {
    const float* X      = (const float*)d_in[0];   // [32,4096,512]
    const float* dec    = (const float*)d_in[1];   // [32,512]
    const float* W_enc  = (const float*)d_in[2];   // [512,512]
    const float* b_enc  = (const float*)d_in[3];   // [512]
    const float* W_dec  = (const float*)d_in[4];   // [512,512]
    const float* b_dec  = (const float*)d_in[5];   // [512]
    const float* v      = (const float*)d_in[6];   // [512]
    float* out = (float*)d_out;                    // [32,1,512]

    char* ws = (char*)d_ws;
    uint4* wpack    = (uint4*)ws;                          // 512 KB
    float* dec_bias = (float*)(ws + (512 << 10));          // 64 KB
    float* scores   = (float*)(ws + (512 << 10) + (64 << 10));   // 512 KB
    float* attn     = (float*)(ws + (1024 << 10) + (64 << 10));  // 512 KB

    hipMemsetAsync(d_out, 0, 32 * EDIM * sizeof(float), stream);

    pack_w   <<<128,  256, 0, stream>>>(W_enc, wpack);
    dec_proj <<<4096, 256, 0, stream>>>(dec, W_dec, b_enc, b_dec, dec_bias);
    score_kernel<<<2048, 256, 0, stream>>>(X, wpack, dec_bias, v, scores);
    softmax_k<<<32,   256, 0, stream>>>(scores, attn);
    context_k<<<512,  256, 0, stream>>>(X, attn, out);
}

// Round 2
// 478.545 us; speedup vs baseline: 1.0816x; 1.0816x over previous
//
#include <hip/hip_runtime.h>
#include <hip/hip_bf16.h>

// Problem constants: B=32, S=4096, E=512, D=512, H=512
#define BATCH 32
#define SEQ   4096
#define EDIM  512
#define HDIM  512

typedef unsigned short u16;
typedef unsigned int   u32;

typedef __bf16 bf16x8 __attribute__((ext_vector_type(8)));
typedef float  f32x4  __attribute__((ext_vector_type(4)));

__device__ __forceinline__ u16 bf_rne(float x) {
    u32 u = __float_as_uint(x);
    u32 r = (u + 0x7fffu + ((u >> 16) & 1u)) >> 16;   // round-to-nearest-even
    return (u16)r;
}
__device__ __forceinline__ u32 pack2(u16 lo, u16 hi) {
    return (u32)lo | ((u32)hi << 16);
}
__device__ __forceinline__ float tanh_fast(float x) {
    float e = __builtin_amdgcn_exp2f(x * 2.88539008177793f);
    return 1.0f - 2.0f * __builtin_amdgcn_rcpf(e + 1.0f);
}

// ---------------------------------------------------------------------------
// Kernel 0: pack W_enc [H][E] fp32 -> bf16 in b-fragment-major layout.
// chunk id = (nsub*16 + kc)*64 + lane; lane holds W[nsub*16+(l&15)][kc*32+(l>>4)*8+j]
// ---------------------------------------------------------------------------
__global__ void pack_w(const float* __restrict__ W, uint4* __restrict__ out) {
    int id   = blockIdx.x * 256 + threadIdx.x;      // 32768 chunks
    int nsub = id >> 10;
    int rem  = id & 1023;
    int kc   = rem >> 6;
    int lane = rem & 63;
    int row  = nsub * 16 + (lane & 15);
    int col  = kc * 32 + (lane >> 4) * 8;
    const float* src = W + row * EDIM + col;
    uint4 o;
    o.x = pack2(bf_rne(src[0]), bf_rne(src[1]));
    o.y = pack2(bf_rne(src[2]), bf_rne(src[3]));
    o.z = pack2(bf_rne(src[4]), bf_rne(src[5]));
    o.w = pack2(bf_rne(src[6]), bf_rne(src[7]));
    out[id] = o;
}

// ---------------------------------------------------------------------------
// Kernel 1: dec_bias[b][h] = dot(dec[b], W_dec[h]) + b_dec[h] + b_enc[h]
// ---------------------------------------------------------------------------
__global__ void dec_proj(const float* __restrict__ dec, const float* __restrict__ Wd,
                         const float* __restrict__ b_enc, const float* __restrict__ b_dec,
                         float* __restrict__ out) {
    int wave = threadIdx.x >> 6, lane = threadIdx.x & 63;
    int p = blockIdx.x * 4 + wave;
    int b = p >> 9, h = p & 511;
    const float4* wr = reinterpret_cast<const float4*>(Wd)  + h * 128;
    const float4* dr = reinterpret_cast<const float4*>(dec) + b * 128;
    float4 w0 = wr[lane * 2], w1 = wr[lane * 2 + 1];
    float4 d0 = dr[lane * 2], d1 = dr[lane * 2 + 1];
    float s = w0.x * d0.x + w0.y * d0.y + w0.z * d0.z + w0.w * d0.w
            + w1.x * d1.x + w1.y * d1.y + w1.z * d1.z + w1.w * d1.w;
#pragma unroll
    for (int m = 1; m < 64; m <<= 1) s += __shfl_xor(s, m, 64);
    if (lane == 0) out[p] = s + b_dec[h] + b_enc[h];
}

// ---------------------------------------------------------------------------
// Kernel 2: fused enc-projection + tanh + v-dot -> scores[131072]
// v2: double-buffered LDS A-tile, ONE barrier per BK=32 chunk, X prefetched a
// full iteration ahead of its ds_write, B-frags hoisted before MFMA loop.
// mfma_f32_16x16x32_bf16: A[m=l&15][k=(l>>4)*8+j]; C/D: m=(l>>4)*4+r, n=l&15.
// ---------------------------------------------------------------------------
__global__ __launch_bounds__(256, 2) void score_kernel(
    const float* __restrict__ X, const uint4* __restrict__ Wp,
    const float* __restrict__ bias, const float* __restrict__ v,
    float* __restrict__ scores)
{
    __shared__ alignas(16) u16 Abuf[2][64 * 40];   // 2 x (64 rows x (32 k + 8 pad))
    __shared__ float sred[4][64];

    const int tid  = threadIdx.x;
    const int wave = tid >> 6, lane = tid & 63;
    const int quad = lane >> 4, l15 = lane & 15;
    const int blk  = blockIdx.x;
    const long row0 = (long)blk * 64;
    const int b = blk >> 6;
    const float4* X4 = reinterpret_cast<const float4*>(X + row0 * EDIM);

    float hb[8], hv[8];
#pragma unroll
    for (int jj = 0; jj < 8; jj++) {
        int h = wave * 128 + jj * 16 + l15;
        hb[jj] = bias[b * HDIM + h];
        hv[jj] = v[h];
    }

    f32x4 acc[4][8] = {};
    float s_acc[16];
#pragma unroll
    for (int i = 0; i < 16; i++) s_acc[i] = 0.f;

    const int r0 = tid >> 3;          // 0..31
    const int c0 = tid & 7;           // float4 col within 32-float chunk
    const int r1 = r0 + 32;

    // preload chunk 0, stage to buf0, prefetch chunk 1
    float4 pa = X4[r0 * 128 + c0];
    float4 pb = X4[r1 * 128 + c0];
    {
        uint2 s0 = make_uint2(pack2(bf_rne(pa.x), bf_rne(pa.y)),
                              pack2(bf_rne(pa.z), bf_rne(pa.w)));
        uint2 s1 = make_uint2(pack2(bf_rne(pb.x), bf_rne(pb.y)),
                              pack2(bf_rne(pb.z), bf_rne(pb.w)));
        *reinterpret_cast<uint2*>(&Abuf[0][r0 * 40 + c0 * 4]) = s0;
        *reinterpret_cast<uint2*>(&Abuf[0][r1 * 40 + c0 * 4]) = s1;
    }
    pa = X4[r0 * 128 + 8 + c0];
    pb = X4[r1 * 128 + 8 + c0];
    __syncthreads();

#pragma unroll
    for (int ch = 0; ch < 16; ch++) {
        const int c = ch & 1;
        // stage chunk ch+1 into the other buffer (regs were loaded last iter)
        if (ch < 15) {
            uint2 s0 = make_uint2(pack2(bf_rne(pa.x), bf_rne(pa.y)),
                                  pack2(bf_rne(pa.z), bf_rne(pa.w)));
            uint2 s1 = make_uint2(pack2(bf_rne(pb.x), bf_rne(pb.y)),
                                  pack2(bf_rne(pb.z), bf_rne(pb.w)));
            *reinterpret_cast<uint2*>(&Abuf[c ^ 1][r0 * 40 + c0 * 4]) = s0;
            *reinterpret_cast<uint2*>(&Abuf[c ^ 1][r1 * 40 + c0 * 4]) = s1;
        }
        // prefetch chunk ch+2 (one full iteration of latency hiding)
        if (ch < 14) {
            int k4 = (ch + 2) * 8;
            pa = X4[r0 * 128 + k4 + c0];
            pb = X4[r1 * 128 + k4 + c0];
        }
        // B-fragments for this chunk: hoist all 8 loads before the MFMA loop
        uint4 braw[8];
#pragma unroll
        for (int jj = 0; jj < 8; jj++)
            braw[jj] = Wp[((wave * 8 + jj) * 16 + ch) * 64 + lane];
        // A-fragments from the current buffer
        bf16x8 af[4];
#pragma unroll
        for (int i = 0; i < 4; i++)
            af[i] = *reinterpret_cast<const bf16x8*>(&Abuf[c][(i * 16 + l15) * 40 + quad * 8]);
#pragma unroll
        for (int jj = 0; jj < 8; jj++) {
            bf16x8 bfr = __builtin_bit_cast(bf16x8, braw[jj]);
#pragma unroll
            for (int i = 0; i < 4; i++)
                acc[i][jj] = __builtin_amdgcn_mfma_f32_16x16x32_bf16(
                    af[i], bfr, acc[i][jj], 0, 0, 0);
        }
        __syncthreads();   // single barrier per chunk
    }

    // epilogue: score contribution v[h]*tanh(acc + bias[h])
#pragma unroll
    for (int i = 0; i < 4; i++)
#pragma unroll
        for (int jj = 0; jj < 8; jj++)
#pragma unroll
            for (int r = 0; r < 4; r++) {
                float val = acc[i][jj][r] + hb[jj];
                s_acc[i * 4 + r] += hv[jj] * tanh_fast(val);
            }

#pragma unroll
    for (int m = 1; m < 16; m <<= 1)
#pragma unroll
        for (int x = 0; x < 16; x++)
            s_acc[x] += __shfl_xor(s_acc[x], m, 16);

    if (l15 == 0) {
#pragma unroll
        for (int x = 0; x < 16; x++) {
            int i = x >> 2, r = x & 3;
            sred[wave][i * 16 + quad * 4 + r] = s_acc[x];
        }
    }
    __syncthreads();
    if (tid < 64) {
        scores[row0 + tid] = sred[0][tid] + sred[1][tid] + sred[2][tid] + sred[3][tid];
    }
}

// ---------------------------------------------------------------------------
// Kernel 3: softmax over S per batch.
// ---------------------------------------------------------------------------
__global__ void softmax_k(const float* __restrict__ scores, float* __restrict__ attn) {
    __shared__ float redmax[4], redsum[4];
    int b = blockIdx.x, t = threadIdx.x;
    int wave = t >> 6, lane = t & 63;
    const float* sb = scores + b * SEQ;
    float vals[16];
    float mx = -1e30f;
#pragma unroll
    for (int i = 0; i < 16; i++) { vals[i] = sb[i * 256 + t]; mx = fmaxf(mx, vals[i]); }
#pragma unroll
    for (int m = 1; m < 64; m <<= 1) mx = fmaxf(mx, __shfl_xor(mx, m, 64));
    if (lane == 0) redmax[wave] = mx;
    __syncthreads();
    mx = fmaxf(fmaxf(redmax[0], redmax[1]), fmaxf(redmax[2], redmax[3]));
    float s = 0.f;
#pragma unroll
    for (int i = 0; i < 16; i++) {
        float e = __builtin_amdgcn_exp2f((vals[i] - mx) * 1.44269504088896f);
        vals[i] = e; s += e;
    }
#pragma unroll
    for (int m = 1; m < 64; m <<= 1) s += __shfl_xor(s, m, 64);
    if (lane == 0) redsum[wave] = s;
    __syncthreads();
    s = redsum[0] + redsum[1] + redsum[2] + redsum[3];
    float inv = 1.0f / s;
    float* ab = attn + b * SEQ;
#pragma unroll
    for (int i = 0; i < 16; i++) ab[i * 256 + t] = vals[i] * inv;
}

// ---------------------------------------------------------------------------
// Kernel 4: context[b][e] = sum_s attn[b][s] * X[b][s][e].
// v2: 2048 blocks (b x 64-seq chunks), batched loads, split accumulators.
// ---------------------------------------------------------------------------
__global__ __launch_bounds__(256) void context_k(const float* __restrict__ X,
                                                 const float* __restrict__ attn,
                                                 float* __restrict__ out) {
    __shared__ float aw[64];
    int blk = blockIdx.x;                 // 32 b x 64 chunks
    int b = blk >> 6, s0 = (blk & 63) << 6;
    int t = threadIdx.x;
    if (t < 64) aw[t] = attn[b * SEQ + s0 + t];
    __syncthreads();
    const float2* Xp = reinterpret_cast<const float2*>(X) + ((long)(b * SEQ + s0)) * 256 + t;
    float ax0 = 0.f, ay0 = 0.f, ax1 = 0.f, ay1 = 0.f;
#pragma unroll 4
    for (int s = 0; s < 64; s += 8) {
        float2 x[8];
#pragma unroll
        for (int k = 0; k < 8; k++) x[k] = Xp[(long)(s + k) * 256];
#pragma unroll
        for (int k = 0; k < 8; k += 2) {
            float w0 = aw[s + k], w1 = aw[s + k + 1];
            ax0 = fmaf(w0, x[k].x,     ax0);
            ay0 = fmaf(w0, x[k].y,     ay0);
            ax1 = fmaf(w1, x[k + 1].x, ax1);
            ay1 = fmaf(w1, x[k + 1].y, ay1);
        }
    }
    atomicAdd(&out[b * EDIM + t * 2],     ax0 + ax1);
    atomicAdd(&out[b * EDIM + t * 2 + 1], ay0 + ay1);
}

// ---------------------------------------------------------------------------
extern "C" void kernel_launch(void* const* d_in, const int* in_sizes, int n_in,
                              void* d_out, int out_size, void* d_ws, size_t ws_size,
                              hipStream_t stream) {
    const float* X      = (const float*)d_in[0];
    const float* dec    = (const float*)d_in[1];
    const float* W_enc  = (const float*)d_in[2];
    const float* b_enc  = (const float*)d_in[3];
    const float* W_dec  = (const float*)d_in[4];
    const float* b_dec  = (const float*)d_in[5];
    const float* v      = (const float*)d_in[6];
    float* out = (float*)d_out;

    char* ws = (char*)d_ws;
    uint4* wpack    = (uint4*)ws;                                 // 512 KB
    float* dec_bias = (float*)(ws + (512 << 10));                 // 64 KB
    float* scores   = (float*)(ws + (512 << 10) + (64 << 10));    // 512 KB
    float* attn     = (float*)(ws + (1024 << 10) + (64 << 10));   // 512 KB

    hipMemsetAsync(d_out, 0, 32 * EDIM * sizeof(float), stream);

    pack_w   <<<128,  256, 0, stream>>>(W_enc, wpack);
    dec_proj <<<4096, 256, 0, stream>>>(dec, W_dec, b_enc, b_dec, dec_bias);
    score_kernel<<<2048, 256, 0, stream>>>(X, wpack, dec_bias, v, scores);
    softmax_k<<<32,   256, 0, stream>>>(scores, attn);
    context_k<<<2048, 256, 0, stream>>>(X, attn, out);
}